// Round 20
// baseline (286.887 us; speedup 1.0000x reference)
//
#include <hip/hip_runtime.h>
#include <hip/hip_bf16.h>

#define B_ 128
#define N_ 320
#define C_ 256
#define H_ 8
#define HQKV 1536
#define DH 1024
#define MROWS 40960
#define EPS 1e-5f
#define SCALE 0.17677669529663687f
#define LOG2E 1.4426950408889634f

typedef __attribute__((ext_vector_type(4))) float f32x4;
typedef __attribute__((ext_vector_type(8))) short short8_t;
typedef __attribute__((ext_vector_type(4))) short short4_t;
typedef __attribute__((ext_vector_type(4))) unsigned short ushort4_t;

__device__ inline float bf2f(unsigned short u) { return __uint_as_float(((unsigned)u) << 16); }
__device__ inline unsigned short f2bf(float f) {
    unsigned u = __float_as_uint(f);
    u += 0x7FFF + ((u >> 16) & 1);
    return (unsigned short)(u >> 16);
}

// sigmoid-form tanh-GELU (8 VALU ops)
__device__ inline float gelu_f(float v) {
    float v2 = v * v;
    float w = fmaf(v2, 0.044715f, 1.0f);
    float z = v * w * (-2.3022098f);
    float e = __builtin_amdgcn_exp2f(z);
    return v * __builtin_amdgcn_rcpf(1.0f + e);
}

#define GLD16(gp, lp)                                                                  \
    __builtin_amdgcn_global_load_lds((const __attribute__((address_space(1))) void*)(gp), \
                                     (__attribute__((address_space(3))) void*)(lp), 16, 0, 0)

__global__ void conv_all(const float* __restrict__ x, const float* __restrict__ wqkv,
                         const float* __restrict__ wproj, unsigned short* __restrict__ xb,
                         unsigned short* __restrict__ wqb, unsigned short* __restrict__ wpb) {
    int i = blockIdx.x * 256 + threadIdx.x;
    const float* src;
    unsigned short* dst;
    int off;
    if (i < 2621440) { src = x; dst = xb; off = i; }
    else if (i < 2719744) { src = wqkv; dst = wqb; off = i - 2621440; }
    else if (i < 2785280) { src = wproj; dst = wpb; off = i - 2719744; }
    else return;
    f32x4 v = ((const f32x4*)src)[off];
    short4_t o;
#pragma unroll
    for (int j = 0; j < 4; ++j) o[j] = (short)f2bf(v[j]);
    ((short4_t*)dst)[off] = o;
}

// ---- GEMM1: 128x256 tile, 512 threads (8 waves 2Mx4N), 2-phase dbuf, XCD swizzle,
// routes q/k/v, fused BN stats ----
__global__ __launch_bounds__(512, 4) void gemm_qkv(const unsigned short* __restrict__ A,
                                                   const unsigned short* __restrict__ Bm,
                                                   unsigned short* __restrict__ qkB,
                                                   unsigned short* __restrict__ vT,
                                                   float* __restrict__ sum1,
                                                   float* __restrict__ sumsq1) {
    __shared__ unsigned short lA[2][128 * 32];
    __shared__ unsigned short lB[2][256 * 32];
    const int tid = threadIdx.x;
    const int lane = tid & 63, wid = tid >> 6;
    const int wm = wid >> 2, wn = wid & 3;
    const int lr = lane & 15, g = lane >> 4, lk = g * 8;
    const int orig = blockIdx.x;
    const int id2 = (orig & 7) * 240 + (orig >> 3);
    const int m0 = (id2 / 6) * 128, n0 = (id2 % 6) * 256;
    const int wb0 = tid & 448;

#define STAGE_QKV(it, buf)                                                               \
    {                                                                                    \
        int k0 = (it) * 32;                                                              \
        GLD16(&A[(size_t)(m0 + (tid >> 2)) * 256 + k0 + (tid & 3) * 8],                  \
              &lA[buf][(size_t)wb0 * 8]);                                                \
        GLD16(&Bm[(size_t)(n0 + (tid >> 2)) * 256 + k0 + (tid & 3) * 8],                 \
              &lB[buf][(size_t)wb0 * 8]);                                                \
        GLD16(&Bm[(size_t)(n0 + 128 + (tid >> 2)) * 256 + k0 + (tid & 3) * 8],           \
              &lB[buf][4096 + (size_t)wb0 * 8]);                                         \
    }

    STAGE_QKV(0, 0);
    f32x4 acc[4][4] = {};
    for (int it = 0; it < 8; ++it) {
        __syncthreads();
        if (it < 7) STAGE_QKV(it + 1, (it + 1) & 1);
        const unsigned short* la = lA[it & 1];
        const unsigned short* lb = lB[it & 1];
        short8_t af[4], bfr[4];
#pragma unroll
        for (int i = 0; i < 4; ++i) af[i] = *(const short8_t*)&la[(wm * 64 + i * 16 + lr) * 32 + lk];
#pragma unroll
        for (int j = 0; j < 4; ++j) bfr[j] = *(const short8_t*)&lb[(wn * 64 + j * 16 + lr) * 32 + lk];
#pragma unroll
        for (int i = 0; i < 4; ++i)
#pragma unroll
            for (int j = 0; j < 4; ++j)
                acc[i][j] = __builtin_amdgcn_mfma_f32_16x16x32_bf16(af[i], bfr[j], acc[i][j], 0, 0, 0);
    }
    int hhj[4], cmj[4];
#pragma unroll
    for (int j = 0; j < 4; ++j) {
        int col = n0 + wn * 64 + j * 16 + lr;
        hhj[j] = col / 192;
        cmj[j] = col - hhj[j] * 192;
    }
    float cs[4] = {0.f, 0.f, 0.f, 0.f}, css[4] = {0.f, 0.f, 0.f, 0.f};
#pragma unroll
    for (int i = 0; i < 4; ++i) {
        int rowbase = m0 + wm * 64 + i * 16 + g * 4;
        int bq = rowbase / 320;
        int n = rowbase - bq * 320;
#pragma unroll
        for (int j = 0; j < 4; ++j) {
            float v0 = acc[i][j][0], v1 = acc[i][j][1], v2 = acc[i][j][2], v3 = acc[i][j][3];
            cs[j] += (v0 + v1) + (v2 + v3);
            css[j] += (v0 * v0 + v1 * v1) + (v2 * v2 + v3 * v3);
            if (cmj[j] < 64) {
                unsigned short* qp = &qkB[((size_t)(bq * 8 + hhj[j]) * 320 + n) * 64 + cmj[j]];
                qp[0] = f2bf(v0); qp[64] = f2bf(v1); qp[128] = f2bf(v2); qp[192] = f2bf(v3);
            } else {
                short4_t o;
                o[0] = (short)f2bf(v0); o[1] = (short)f2bf(v1);
                o[2] = (short)f2bf(v2); o[3] = (short)f2bf(v3);
                *(short4_t*)&vT[((size_t)(bq * 8 + hhj[j]) * 128 + (cmj[j] - 64)) * 320 + n] = o;
            }
        }
    }
    __syncthreads();
    float* red_s = (float*)lA;
    float* red_ss = (float*)lB;
#pragma unroll
    for (int j = 0; j < 4; ++j) {
        int c = wn * 64 + j * 16 + lr;
        red_s[(wm * 4 + g) * 256 + c] = cs[j];
        red_ss[(wm * 4 + g) * 256 + c] = css[j];
    }
    __syncthreads();
    if (tid < 256) {
        float s = 0.f;
#pragma unroll
        for (int u = 0; u < 8; ++u) s += red_s[u * 256 + tid];
        atomicAdd(&sum1[n0 + tid], s);
    } else if (tid < 512) {
        int c = tid - 256;
        float s = 0.f;
#pragma unroll
        for (int u = 0; u < 8; ++u) s += red_ss[u * 256 + c];
        atomicAdd(&sumsq1[n0 + c], s);
    }
}

// ---- GEMM2: 64x256 tile (single N-tile: A read once), 2-phase dbuf, fused stats ----
__global__ __launch_bounds__(256, 4) void gemm_proj(const unsigned short* __restrict__ A,
                                                    const unsigned short* __restrict__ Bm,
                                                    float* __restrict__ Cout,
                                                    float* __restrict__ sum2,
                                                    float* __restrict__ sumsq2) {
    __shared__ unsigned short lA[2][64 * 32];
    __shared__ unsigned short lB[2][256 * 32];
    const int tid = threadIdx.x;
    const int lane = tid & 63, wid = tid >> 6;
    const int wn = wid;
    const int lr = lane & 15, g = lane >> 4, lk = g * 8;
    const int m0 = blockIdx.x * 64;
    const int wb0 = tid & 192;

#define STAGE_PROJ(it, buf)                                                              \
    {                                                                                    \
        int k0 = (it) * 32;                                                              \
        GLD16(&A[(size_t)(m0 + (tid >> 2)) * 1024 + k0 + (tid & 3) * 8],                 \
              &lA[buf][(size_t)wb0 * 8]);                                                \
        GLD16(&Bm[(size_t)(tid >> 2) * 1024 + k0 + (tid & 3) * 8],                       \
              &lB[buf][(size_t)wb0 * 8]);                                                \
        GLD16(&Bm[(size_t)(64 + (tid >> 2)) * 1024 + k0 + (tid & 3) * 8],                \
              &lB[buf][2048 + (size_t)wb0 * 8]);                                         \
        GLD16(&Bm[(size_t)(128 + (tid >> 2)) * 1024 + k0 + (tid & 3) * 8],               \
              &lB[buf][4096 + (size_t)wb0 * 8]);                                         \
        GLD16(&Bm[(size_t)(192 + (tid >> 2)) * 1024 + k0 + (tid & 3) * 8],               \
              &lB[buf][6144 + (size_t)wb0 * 8]);                                         \
    }

    STAGE_PROJ(0, 0);
    f32x4 acc[4][4] = {};
    for (int it = 0; it < 32; ++it) {
        __syncthreads();
        if (it < 31) STAGE_PROJ(it + 1, (it + 1) & 1);
        const unsigned short* la = lA[it & 1];
        const unsigned short* lb = lB[it & 1];
        short8_t af[4], bfr[4];
#pragma unroll
        for (int i = 0; i < 4; ++i) af[i] = *(const short8_t*)&la[(i * 16 + lr) * 32 + lk];
#pragma unroll
        for (int j = 0; j < 4; ++j) bfr[j] = *(const short8_t*)&lb[(wn * 64 + j * 16 + lr) * 32 + lk];
#pragma unroll
        for (int i = 0; i < 4; ++i)
#pragma unroll
            for (int j = 0; j < 4; ++j)
                acc[i][j] = __builtin_amdgcn_mfma_f32_16x16x32_bf16(af[i], bfr[j], acc[i][j], 0, 0, 0);
    }
    float cs[4] = {0.f, 0.f, 0.f, 0.f}, css[4] = {0.f, 0.f, 0.f, 0.f};
#pragma unroll
    for (int i = 0; i < 4; ++i) {
#pragma unroll
        for (int r = 0; r < 4; ++r) {
            int row = m0 + i * 16 + g * 4 + r;
#pragma unroll
            for (int j = 0; j < 4; ++j) {
                float val = acc[i][j][r];
                cs[j] += val;
                css[j] += val * val;
                Cout[(size_t)row * 256 + wn * 64 + j * 16 + lr] = val;
            }
        }
    }
    __syncthreads();
    float* red_s = (float*)lA;
    float* red_ss = (float*)lB;
#pragma unroll
    for (int j = 0; j < 4; ++j) {
        int c = wn * 64 + j * 16 + lr;
        red_s[g * 256 + c] = cs[j];
        red_ss[g * 256 + c] = css[j];
    }
    __syncthreads();
    {
        float s = 0.f, ss = 0.f;
#pragma unroll
        for (int u = 0; u < 4; ++u) {
            s += red_s[u * 256 + tid];
            ss += red_ss[u * 256 + tid];
        }
        atomicAdd(&sum2[tid], s);
        atomicAdd(&sumsq2[tid], ss);
    }
}

__global__ void bn_finalize(const float* __restrict__ sum, const float* __restrict__ sumsq,
                            const float* __restrict__ g, const float* __restrict__ b,
                            float* __restrict__ scale, float* __restrict__ shift, int C, float invM) {
    int c = blockIdx.x * 256 + threadIdx.x;
    if (c < C) {
        float mean = sum[c] * invM;
        float var = sumsq[c] * invM - mean * mean;
        float sc = g[c] * rsqrtf(var + EPS);
        scale[c] = sc;
        shift[c] = b[c] - mean * sc;
    }
}

// uk with w2 built in LDS preamble
__global__ void uk_kernel(const unsigned short* __restrict__ qkB, const float* __restrict__ scale1,
                          const float* __restrict__ shift1, float* __restrict__ uk) {
    __shared__ float w2l[256];
    {
        int c = threadIdx.x;
        int hh = c >> 5, cc = c & 31;
        int qch = hh * 192 + cc;
        w2l[c] = shift1[qch] * scale1[qch + 32] * (SCALE * LOG2E);
    }
    __syncthreads();
    int idx = blockIdx.x * 256 + threadIdx.x;
    if (idx < 128 * 8 * 320) {
        int bh = idx / 320;
        int h = bh & 7;
        const unsigned short* kp = &qkB[(size_t)idx * 64 + 32];
        float s = 0.f;
#pragma unroll
        for (int c4 = 0; c4 < 4; ++c4) {
            short8_t kk = *(const short8_t*)&kp[c4 * 8];
#pragma unroll
            for (int j = 0; j < 8; ++j) s += bf2f((unsigned short)kk[j]) * w2l[(h << 5) + c4 * 8 + j];
        }
        uk[idx] = s;
    }
}

// bias re-tiled: biasb[((h*80 + n/4)*320 + m)*4 + (n%4)] = bf16(ab[h][idxs[n][m]]*log2e)
__global__ void bias_build(const float* __restrict__ ab, const int* __restrict__ idxs,
                           unsigned short* __restrict__ biasb, int n_off) {
    int i = blockIdx.x * 256 + threadIdx.x;
    if (i < H_ * N_ * N_) {
        int r = i & 3;
        int m = (i >> 2) % 320;
        int nq = ((i >> 2) / 320) % 80;
        int h = i / 102400;
        int n = nq * 4 + r;
        biasb[i] = f2bf(ab[h * n_off + idxs[n * 320 + m]] * LOG2E);
    }
}

// ---- attention v12: kv-half split, spill-free, launch_bounds(256,8) -> 64-VGPR budget
// (compiler already uses 60). LDS 25.9KB -> up to 6 blocks/CU (75% occ). ----
__global__ __launch_bounds__(256, 8) void attn_kernel(const unsigned short* __restrict__ qkB,
                                                      const unsigned short* __restrict__ vT,
                                                      const float* __restrict__ uk,
                                                      const unsigned short* __restrict__ biasb,
                                                      const float* __restrict__ scale1,
                                                      const float* __restrict__ shift1,
                                                      unsigned short* __restrict__ attnout) {
    __shared__ unsigned short Plds[4][5][16][40];
    __shared__ float sums[64];
    const int tid = threadIdx.x;
    const int lane = tid & 63, wid = tid >> 6;
    const int lr = lane & 15, g = lane >> 4;
    const int h = blockIdx.x;
    const int b = blockIdx.y / 5, qt = blockIdx.y % 5;
    const int bh = b * 8 + h;

    int qrow = qt * 64 + wid * 16 + lr;
    short8_t qraw = *(const short8_t*)&qkB[((size_t)bh * 320 + qrow) * 64 + g * 8];
    short8_t aq;
    const int cq = h * 192 + g * 8;
#pragma unroll
    for (int j = 0; j < 8; ++j) {
        float w = scale1[cq + j] * scale1[cq + 32 + j] * (SCALE * LOG2E);
        aq[j] = (short)f2bf(bf2f((unsigned short)qraw[j]) * w);
    }

    const unsigned short* Kbase = &qkB[(size_t)bh * 320 * 64 + 32 + g * 8];
    const int nloc0 = qt * 64 + wid * 16 + g * 4;
    const unsigned short* biasrow = &biasb[((size_t)h * 80 + (nloc0 >> 2)) * 1280];
    const float* ukrow = &uk[(size_t)bh * 320];
    const unsigned short* Vb = &vT[(size_t)bh * 128 * 320 + g * 8];

    float sumr[4] = {0.f, 0.f, 0.f, 0.f};
    f32x4 oacc[4][2] = {};
#pragma unroll
    for (int half = 0; half < 2; ++half) {
        const int mb = half * 160;
        // phase 1: 10 QK^T MFMAs for this half
        f32x4 sacc[10];
        __builtin_amdgcn_s_setprio(1);
#pragma unroll
        for (int t = 0; t < 10; ++t) {
            short8_t bk = *(const short8_t*)&Kbase[(size_t)(mb + t * 16 + lr) * 64];
            f32x4 z = {};
            sacc[t] = __builtin_amdgcn_mfma_f32_16x16x32_bf16(aq, bk, z, 0, 0, 0);
        }
        __builtin_amdgcn_s_setprio(0);
        // phase 2: coalesced ushort4 bias + uk + exp2 -> P slab
#pragma unroll
        for (int t = 0; t < 10; ++t) {
            int m = mb + t * 16 + lr;
            float ukv = ukrow[m];
            ushort4_t b4 = *(const ushort4_t*)&biasrow[m * 4];
#pragma unroll
            for (int r = 0; r < 4; ++r) {
                float s = sacc[t][r] + ukv + bf2f(b4[r]);
                float p = __builtin_amdgcn_exp2f(s);
                sumr[r] += p;
                Plds[wid][t >> 1][g * 4 + r][(t & 1) * 16 + lr] = f2bf(p);
            }
        }
        __syncthreads();
        // phase 3: PV for this half; wave owns O-cols [wid*32, +32); reads all 4 P slabs
        __builtin_amdgcn_s_setprio(1);
#pragma unroll
        for (int t = 0; t < 5; ++t) {
            short8_t bv0 = *(const short8_t*)&Vb[(size_t)(wid * 32 + lr) * 320 + mb + t * 32];
            short8_t bv1 = *(const short8_t*)&Vb[(size_t)(wid * 32 + 16 + lr) * 320 + mb + t * 32];
#pragma unroll
            for (int qw = 0; qw < 4; ++qw) {
                short8_t ap = *(short8_t*)&Plds[qw][t][lr][g * 8];
                oacc[qw][0] = __builtin_amdgcn_mfma_f32_16x16x32_bf16(ap, bv0, oacc[qw][0], 0, 0, 0);
                oacc[qw][1] = __builtin_amdgcn_mfma_f32_16x16x32_bf16(ap, bv1, oacc[qw][1], 0, 0, 0);
            }
        }
        __builtin_amdgcn_s_setprio(0);
        __syncthreads();  // Plds reused next half
    }

    // rowsum reduce + publish
#pragma unroll
    for (int r = 0; r < 4; ++r) {
#pragma unroll
        for (int ms = 1; ms < 16; ms <<= 1) sumr[r] += __shfl_xor(sumr[r], ms);
    }
    if (lr == 0) {
#pragma unroll
        for (int r = 0; r < 4; ++r) sums[wid * 16 + g * 4 + r] = sumr[r];
    }
    __syncthreads();

    // epilogue: normalize, fold V-BN, GELU
    float svv[2], tvv[2];
#pragma unroll
    for (int dtl = 0; dtl < 2; ++dtl) {
        int ch = h * 192 + 64 + wid * 32 + dtl * 16 + lr;
        svv[dtl] = scale1[ch];
        tvv[dtl] = shift1[ch];
    }
#pragma unroll
    for (int qw = 0; qw < 4; ++qw) {
#pragma unroll
        for (int r = 0; r < 4; ++r) {
            float inv = __builtin_amdgcn_rcpf(sums[qw * 16 + g * 4 + r]);
            size_t nrow = (size_t)b * 320 + qt * 64 + qw * 16 + g * 4 + r;
#pragma unroll
            for (int dtl = 0; dtl < 2; ++dtl) {
                float v = oacc[qw][dtl][r] * inv * svv[dtl] + tvv[dtl];
                attnout[nrow * 1024 + h * 128 + wid * 32 + dtl * 16 + lr] = f2bf(gelu_f(v));
            }
        }
    }
}

// BN2 finalize folded into apply
__global__ void bn_apply(float* __restrict__ out, const float* __restrict__ sum2,
                         const float* __restrict__ sumsq2, const float* __restrict__ g2,
                         const float* __restrict__ b2) {
    __shared__ float sc[256], sh[256];
    {
        int c = threadIdx.x;
        float mean = sum2[c] * (1.0f / MROWS);
        float var = sumsq2[c] * (1.0f / MROWS) - mean * mean;
        float s = g2[c] * rsqrtf(var + EPS);
        sc[c] = s;
        sh[c] = b2[c] - mean * s;
    }
    __syncthreads();
    int i = blockIdx.x * 256 + threadIdx.x;
    const int total = MROWS * C_ / 4;
    for (; i < total; i += gridDim.x * 256) {
        f32x4 v = *(const f32x4*)&out[(size_t)i * 4];
        int c = (i * 4) & 255;
        f32x4 o;
#pragma unroll
        for (int j = 0; j < 4; ++j) o[j] = v[j] * sc[c + j] + sh[c + j];
        *(f32x4*)&out[(size_t)i * 4] = o;
    }
}

extern "C" void kernel_launch(void* const* d_in, const int* in_sizes, int n_in,
                              void* d_out, int out_size, void* d_ws, size_t ws_size,
                              hipStream_t stream) {
    const float* x = (const float*)d_in[0];
    const float* Wqkv = (const float*)d_in[1];
    const float* g1 = (const float*)d_in[2];
    const float* b1 = (const float*)d_in[3];
    const float* ab = (const float*)d_in[4];
    const float* Wproj = (const float*)d_in[5];
    const float* g2 = (const float*)d_in[6];
    const float* b2 = (const float*)d_in[7];
    const int* idxs = (const int*)d_in[8];
    const int n_off = in_sizes[4] / H_;

    char* ws = (char*)d_ws;
    unsigned short* qkB = (unsigned short*)ws;                       // 41.9MB
    unsigned short* vT = (unsigned short*)(ws + 41943040);           // 83.9MB
    unsigned short* attnout = (unsigned short*)(ws + 125829120);     // 83.9MB
    unsigned short* xb = attnout;                                    // overlap: dead before attn
    unsigned short* biasb = (unsigned short*)(ws + 209715200);       // bf16, re-tiled, *log2e
    float* uk = (float*)(ws + 212992000);
    unsigned short* wqb = (unsigned short*)(ws + 214302720);
    unsigned short* wpb = (unsigned short*)(ws + 215089152);
    float* stats = (float*)(ws + 215613440);
    float* sum1 = stats;
    float* sumsq1 = stats + 1536;
    float* sum2 = stats + 3072;
    float* sumsq2 = sum2 + 256;
    float* scale1 = sumsq2 + 256;
    float* shift1 = scale1 + 1536;

    hipMemsetAsync(stats, 0, 3584 * 4, stream);
    conv_all<<<dim3(10880), 256, 0, stream>>>(x, Wqkv, Wproj, xb, wqb, wpb);
    bias_build<<<dim3(3200), 256, 0, stream>>>(ab, idxs, biasb, n_off);
    gemm_qkv<<<dim3(1920), 512, 0, stream>>>(xb, wqb, qkB, vT, sum1, sumsq1);
    bn_finalize<<<dim3(6), 256, 0, stream>>>(sum1, sumsq1, g1, b1, scale1, shift1, 1536, 1.0f / MROWS);
    uk_kernel<<<dim3(1280), 256, 0, stream>>>(qkB, scale1, shift1, uk);
    attn_kernel<<<dim3(8, 640), 256, 0, stream>>>(qkB, vT, uk, biasb, scale1, shift1, attnout);
    gemm_proj<<<dim3(640), 256, 0, stream>>>(attnout, wpb, (float*)d_out, sum2, sumsq2);
    bn_apply<<<dim3(2048), 256, 0, stream>>>((float*)d_out, sum2, sumsq2, g2, b2);
}

// Round 21
// 278.545 us; speedup vs baseline: 1.0299x; 1.0299x over previous
//
#include <hip/hip_runtime.h>
#include <hip/hip_bf16.h>

#define B_ 128
#define N_ 320
#define C_ 256
#define H_ 8
#define HQKV 1536
#define DH 1024
#define MROWS 40960
#define EPS 1e-5f
#define SCALE 0.17677669529663687f
#define LOG2E 1.4426950408889634f

typedef __attribute__((ext_vector_type(4))) float f32x4;
typedef __attribute__((ext_vector_type(8))) short short8_t;
typedef __attribute__((ext_vector_type(4))) short short4_t;
typedef __attribute__((ext_vector_type(4))) unsigned short ushort4_t;

__device__ inline float bf2f(unsigned short u) { return __uint_as_float(((unsigned)u) << 16); }
__device__ inline unsigned short f2bf(float f) {
    unsigned u = __float_as_uint(f);
    u += 0x7FFF + ((u >> 16) & 1);
    return (unsigned short)(u >> 16);
}

// sigmoid-form tanh-GELU (8 VALU ops)
__device__ inline float gelu_f(float v) {
    float v2 = v * v;
    float w = fmaf(v2, 0.044715f, 1.0f);
    float z = v * w * (-2.3022098f);
    float e = __builtin_amdgcn_exp2f(z);
    return v * __builtin_amdgcn_rcpf(1.0f + e);
}

#define GLD16(gp, lp)                                                                  \
    __builtin_amdgcn_global_load_lds((const __attribute__((address_space(1))) void*)(gp), \
                                     (__attribute__((address_space(3))) void*)(lp), 16, 0, 0)

__global__ void conv_all(const float* __restrict__ x, const float* __restrict__ wqkv,
                         const float* __restrict__ wproj, unsigned short* __restrict__ xb,
                         unsigned short* __restrict__ wqb, unsigned short* __restrict__ wpb) {
    int i = blockIdx.x * 256 + threadIdx.x;
    const float* src;
    unsigned short* dst;
    int off;
    if (i < 2621440) { src = x; dst = xb; off = i; }
    else if (i < 2719744) { src = wqkv; dst = wqb; off = i - 2621440; }
    else if (i < 2785280) { src = wproj; dst = wpb; off = i - 2719744; }
    else return;
    f32x4 v = ((const f32x4*)src)[off];
    short4_t o;
#pragma unroll
    for (int j = 0; j < 4; ++j) o[j] = (short)f2bf(v[j]);
    ((short4_t*)dst)[off] = o;
}

// ---- GEMM1: 128x256 tile, 512 threads (8 waves 2Mx4N), 2-phase dbuf, XCD swizzle,
// routes q/k/v, fused BN stats ----
__global__ __launch_bounds__(512, 4) void gemm_qkv(const unsigned short* __restrict__ A,
                                                   const unsigned short* __restrict__ Bm,
                                                   unsigned short* __restrict__ qkB,
                                                   unsigned short* __restrict__ vT,
                                                   float* __restrict__ sum1,
                                                   float* __restrict__ sumsq1) {
    __shared__ unsigned short lA[2][128 * 32];
    __shared__ unsigned short lB[2][256 * 32];
    const int tid = threadIdx.x;
    const int lane = tid & 63, wid = tid >> 6;
    const int wm = wid >> 2, wn = wid & 3;
    const int lr = lane & 15, g = lane >> 4, lk = g * 8;
    const int orig = blockIdx.x;
    const int id2 = (orig & 7) * 240 + (orig >> 3);
    const int m0 = (id2 / 6) * 128, n0 = (id2 % 6) * 256;
    const int wb0 = tid & 448;

#define STAGE_QKV(it, buf)                                                               \
    {                                                                                    \
        int k0 = (it) * 32;                                                              \
        GLD16(&A[(size_t)(m0 + (tid >> 2)) * 256 + k0 + (tid & 3) * 8],                  \
              &lA[buf][(size_t)wb0 * 8]);                                                \
        GLD16(&Bm[(size_t)(n0 + (tid >> 2)) * 256 + k0 + (tid & 3) * 8],                 \
              &lB[buf][(size_t)wb0 * 8]);                                                \
        GLD16(&Bm[(size_t)(n0 + 128 + (tid >> 2)) * 256 + k0 + (tid & 3) * 8],           \
              &lB[buf][4096 + (size_t)wb0 * 8]);                                         \
    }

    STAGE_QKV(0, 0);
    f32x4 acc[4][4] = {};
    for (int it = 0; it < 8; ++it) {
        __syncthreads();
        if (it < 7) STAGE_QKV(it + 1, (it + 1) & 1);
        const unsigned short* la = lA[it & 1];
        const unsigned short* lb = lB[it & 1];
        short8_t af[4], bfr[4];
#pragma unroll
        for (int i = 0; i < 4; ++i) af[i] = *(const short8_t*)&la[(wm * 64 + i * 16 + lr) * 32 + lk];
#pragma unroll
        for (int j = 0; j < 4; ++j) bfr[j] = *(const short8_t*)&lb[(wn * 64 + j * 16 + lr) * 32 + lk];
#pragma unroll
        for (int i = 0; i < 4; ++i)
#pragma unroll
            for (int j = 0; j < 4; ++j)
                acc[i][j] = __builtin_amdgcn_mfma_f32_16x16x32_bf16(af[i], bfr[j], acc[i][j], 0, 0, 0);
    }
    int hhj[4], cmj[4];
#pragma unroll
    for (int j = 0; j < 4; ++j) {
        int col = n0 + wn * 64 + j * 16 + lr;
        hhj[j] = col / 192;
        cmj[j] = col - hhj[j] * 192;
    }
    float cs[4] = {0.f, 0.f, 0.f, 0.f}, css[4] = {0.f, 0.f, 0.f, 0.f};
#pragma unroll
    for (int i = 0; i < 4; ++i) {
        int rowbase = m0 + wm * 64 + i * 16 + g * 4;
        int bq = rowbase / 320;
        int n = rowbase - bq * 320;
#pragma unroll
        for (int j = 0; j < 4; ++j) {
            float v0 = acc[i][j][0], v1 = acc[i][j][1], v2 = acc[i][j][2], v3 = acc[i][j][3];
            cs[j] += (v0 + v1) + (v2 + v3);
            css[j] += (v0 * v0 + v1 * v1) + (v2 * v2 + v3 * v3);
            if (cmj[j] < 64) {
                unsigned short* qp = &qkB[((size_t)(bq * 8 + hhj[j]) * 320 + n) * 64 + cmj[j]];
                qp[0] = f2bf(v0); qp[64] = f2bf(v1); qp[128] = f2bf(v2); qp[192] = f2bf(v3);
            } else {
                short4_t o;
                o[0] = (short)f2bf(v0); o[1] = (short)f2bf(v1);
                o[2] = (short)f2bf(v2); o[3] = (short)f2bf(v3);
                *(short4_t*)&vT[((size_t)(bq * 8 + hhj[j]) * 128 + (cmj[j] - 64)) * 320 + n] = o;
            }
        }
    }
    __syncthreads();
    float* red_s = (float*)lA;
    float* red_ss = (float*)lB;
#pragma unroll
    for (int j = 0; j < 4; ++j) {
        int c = wn * 64 + j * 16 + lr;
        red_s[(wm * 4 + g) * 256 + c] = cs[j];
        red_ss[(wm * 4 + g) * 256 + c] = css[j];
    }
    __syncthreads();
    if (tid < 256) {
        float s = 0.f;
#pragma unroll
        for (int u = 0; u < 8; ++u) s += red_s[u * 256 + tid];
        atomicAdd(&sum1[n0 + tid], s);
    } else if (tid < 512) {
        int c = tid - 256;
        float s = 0.f;
#pragma unroll
        for (int u = 0; u < 8; ++u) s += red_ss[u * 256 + c];
        atomicAdd(&sumsq1[n0 + c], s);
    }
}

// ---- GEMM2: 64x256 tile (single N-tile: A read once), 2-phase dbuf, fused stats ----
__global__ __launch_bounds__(256, 4) void gemm_proj(const unsigned short* __restrict__ A,
                                                    const unsigned short* __restrict__ Bm,
                                                    float* __restrict__ Cout,
                                                    float* __restrict__ sum2,
                                                    float* __restrict__ sumsq2) {
    __shared__ unsigned short lA[2][64 * 32];
    __shared__ unsigned short lB[2][256 * 32];
    const int tid = threadIdx.x;
    const int lane = tid & 63, wid = tid >> 6;
    const int wn = wid;
    const int lr = lane & 15, g = lane >> 4, lk = g * 8;
    const int m0 = blockIdx.x * 64;
    const int wb0 = tid & 192;

#define STAGE_PROJ(it, buf)                                                              \
    {                                                                                    \
        int k0 = (it) * 32;                                                              \
        GLD16(&A[(size_t)(m0 + (tid >> 2)) * 1024 + k0 + (tid & 3) * 8],                 \
              &lA[buf][(size_t)wb0 * 8]);                                                \
        GLD16(&Bm[(size_t)(tid >> 2) * 1024 + k0 + (tid & 3) * 8],                       \
              &lB[buf][(size_t)wb0 * 8]);                                                \
        GLD16(&Bm[(size_t)(64 + (tid >> 2)) * 1024 + k0 + (tid & 3) * 8],                \
              &lB[buf][2048 + (size_t)wb0 * 8]);                                         \
        GLD16(&Bm[(size_t)(128 + (tid >> 2)) * 1024 + k0 + (tid & 3) * 8],               \
              &lB[buf][4096 + (size_t)wb0 * 8]);                                         \
        GLD16(&Bm[(size_t)(192 + (tid >> 2)) * 1024 + k0 + (tid & 3) * 8],               \
              &lB[buf][6144 + (size_t)wb0 * 8]);                                         \
    }

    STAGE_PROJ(0, 0);
    f32x4 acc[4][4] = {};
    for (int it = 0; it < 32; ++it) {
        __syncthreads();
        if (it < 31) STAGE_PROJ(it + 1, (it + 1) & 1);
        const unsigned short* la = lA[it & 1];
        const unsigned short* lb = lB[it & 1];
        short8_t af[4], bfr[4];
#pragma unroll
        for (int i = 0; i < 4; ++i) af[i] = *(const short8_t*)&la[(i * 16 + lr) * 32 + lk];
#pragma unroll
        for (int j = 0; j < 4; ++j) bfr[j] = *(const short8_t*)&lb[(wn * 64 + j * 16 + lr) * 32 + lk];
#pragma unroll
        for (int i = 0; i < 4; ++i)
#pragma unroll
            for (int j = 0; j < 4; ++j)
                acc[i][j] = __builtin_amdgcn_mfma_f32_16x16x32_bf16(af[i], bfr[j], acc[i][j], 0, 0, 0);
    }
    float cs[4] = {0.f, 0.f, 0.f, 0.f}, css[4] = {0.f, 0.f, 0.f, 0.f};
#pragma unroll
    for (int i = 0; i < 4; ++i) {
#pragma unroll
        for (int r = 0; r < 4; ++r) {
            int row = m0 + i * 16 + g * 4 + r;
#pragma unroll
            for (int j = 0; j < 4; ++j) {
                float val = acc[i][j][r];
                cs[j] += val;
                css[j] += val * val;
                Cout[(size_t)row * 256 + wn * 64 + j * 16 + lr] = val;
            }
        }
    }
    __syncthreads();
    float* red_s = (float*)lA;
    float* red_ss = (float*)lB;
#pragma unroll
    for (int j = 0; j < 4; ++j) {
        int c = wn * 64 + j * 16 + lr;
        red_s[g * 256 + c] = cs[j];
        red_ss[g * 256 + c] = css[j];
    }
    __syncthreads();
    {
        float s = 0.f, ss = 0.f;
#pragma unroll
        for (int u = 0; u < 4; ++u) {
            s += red_s[u * 256 + tid];
            ss += red_ss[u * 256 + tid];
        }
        atomicAdd(&sum2[tid], s);
        atomicAdd(&sumsq2[tid], ss);
    }
}

__global__ void bn_finalize(const float* __restrict__ sum, const float* __restrict__ sumsq,
                            const float* __restrict__ g, const float* __restrict__ b,
                            float* __restrict__ scale, float* __restrict__ shift, int C, float invM) {
    int c = blockIdx.x * 256 + threadIdx.x;
    if (c < C) {
        float mean = sum[c] * invM;
        float var = sumsq[c] * invM - mean * mean;
        float sc = g[c] * rsqrtf(var + EPS);
        scale[c] = sc;
        shift[c] = b[c] - mean * sc;
    }
}

// uk with w2 built in LDS preamble
__global__ void uk_kernel(const unsigned short* __restrict__ qkB, const float* __restrict__ scale1,
                          const float* __restrict__ shift1, float* __restrict__ uk) {
    __shared__ float w2l[256];
    {
        int c = threadIdx.x;
        int hh = c >> 5, cc = c & 31;
        int qch = hh * 192 + cc;
        w2l[c] = shift1[qch] * scale1[qch + 32] * (SCALE * LOG2E);
    }
    __syncthreads();
    int idx = blockIdx.x * 256 + threadIdx.x;
    if (idx < 128 * 8 * 320) {
        int bh = idx / 320;
        int h = bh & 7;
        const unsigned short* kp = &qkB[(size_t)idx * 64 + 32];
        float s = 0.f;
#pragma unroll
        for (int c4 = 0; c4 < 4; ++c4) {
            short8_t kk = *(const short8_t*)&kp[c4 * 8];
#pragma unroll
            for (int j = 0; j < 8; ++j) s += bf2f((unsigned short)kk[j]) * w2l[(h << 5) + c4 * 8 + j];
        }
        uk[idx] = s;
    }
}

// bias re-tiled: biasb[((h*80 + n/4)*320 + m)*4 + (n%4)] = bf16(ab[h][idxs[n][m]]*log2e)
__global__ void bias_build(const float* __restrict__ ab, const int* __restrict__ idxs,
                           unsigned short* __restrict__ biasb, int n_off) {
    int i = blockIdx.x * 256 + threadIdx.x;
    if (i < H_ * N_ * N_) {
        int r = i & 3;
        int m = (i >> 2) % 320;
        int nq = ((i >> 2) / 320) % 80;
        int h = i / 102400;
        int n = nq * 4 + r;
        biasb[i] = f2bf(ab[h * n_off + idxs[n * 320 + m]] * LOG2E);
    }
}

// ---- attention (R19 final): kv-half split, spill-free, launch_bounds(256,4) ----
__global__ __launch_bounds__(256, 4) void attn_kernel(const unsigned short* __restrict__ qkB,
                                                      const unsigned short* __restrict__ vT,
                                                      const float* __restrict__ uk,
                                                      const unsigned short* __restrict__ biasb,
                                                      const float* __restrict__ scale1,
                                                      const float* __restrict__ shift1,
                                                      unsigned short* __restrict__ attnout) {
    __shared__ unsigned short Plds[4][5][16][40];
    __shared__ float sums[64];
    const int tid = threadIdx.x;
    const int lane = tid & 63, wid = tid >> 6;
    const int lr = lane & 15, g = lane >> 4;
    const int h = blockIdx.x;
    const int b = blockIdx.y / 5, qt = blockIdx.y % 5;
    const int bh = b * 8 + h;

    int qrow = qt * 64 + wid * 16 + lr;
    short8_t qraw = *(const short8_t*)&qkB[((size_t)bh * 320 + qrow) * 64 + g * 8];
    short8_t aq;
    const int cq = h * 192 + g * 8;
#pragma unroll
    for (int j = 0; j < 8; ++j) {
        float w = scale1[cq + j] * scale1[cq + 32 + j] * (SCALE * LOG2E);
        aq[j] = (short)f2bf(bf2f((unsigned short)qraw[j]) * w);
    }

    const unsigned short* Kbase = &qkB[(size_t)bh * 320 * 64 + 32 + g * 8];
    const int nloc0 = qt * 64 + wid * 16 + g * 4;
    const unsigned short* biasrow = &biasb[((size_t)h * 80 + (nloc0 >> 2)) * 1280];
    const float* ukrow = &uk[(size_t)bh * 320];
    const unsigned short* Vb = &vT[(size_t)bh * 128 * 320 + g * 8];

    float sumr[4] = {0.f, 0.f, 0.f, 0.f};
    f32x4 oacc[4][2] = {};
#pragma unroll
    for (int half = 0; half < 2; ++half) {
        const int mb = half * 160;
        // phase 1: 10 QK^T MFMAs for this half
        f32x4 sacc[10];
        __builtin_amdgcn_s_setprio(1);
#pragma unroll
        for (int t = 0; t < 10; ++t) {
            short8_t bk = *(const short8_t*)&Kbase[(size_t)(mb + t * 16 + lr) * 64];
            f32x4 z = {};
            sacc[t] = __builtin_amdgcn_mfma_f32_16x16x32_bf16(aq, bk, z, 0, 0, 0);
        }
        __builtin_amdgcn_s_setprio(0);
        // phase 2: coalesced ushort4 bias + uk + exp2 -> P slab
#pragma unroll
        for (int t = 0; t < 10; ++t) {
            int m = mb + t * 16 + lr;
            float ukv = ukrow[m];
            ushort4_t b4 = *(const ushort4_t*)&biasrow[m * 4];
#pragma unroll
            for (int r = 0; r < 4; ++r) {
                float s = sacc[t][r] + ukv + bf2f(b4[r]);
                float p = __builtin_amdgcn_exp2f(s);
                sumr[r] += p;
                Plds[wid][t >> 1][g * 4 + r][(t & 1) * 16 + lr] = f2bf(p);
            }
        }
        __syncthreads();
        // phase 3: PV for this half; wave owns O-cols [wid*32, +32); reads all 4 P slabs
        __builtin_amdgcn_s_setprio(1);
#pragma unroll
        for (int t = 0; t < 5; ++t) {
            short8_t bv0 = *(const short8_t*)&Vb[(size_t)(wid * 32 + lr) * 320 + mb + t * 32];
            short8_t bv1 = *(const short8_t*)&Vb[(size_t)(wid * 32 + 16 + lr) * 320 + mb + t * 32];
#pragma unroll
            for (int qw = 0; qw < 4; ++qw) {
                short8_t ap = *(short8_t*)&Plds[qw][t][lr][g * 8];
                oacc[qw][0] = __builtin_amdgcn_mfma_f32_16x16x32_bf16(ap, bv0, oacc[qw][0], 0, 0, 0);
                oacc[qw][1] = __builtin_amdgcn_mfma_f32_16x16x32_bf16(ap, bv1, oacc[qw][1], 0, 0, 0);
            }
        }
        __builtin_amdgcn_s_setprio(0);
        __syncthreads();  // Plds reused next half
    }

    // rowsum reduce + publish
#pragma unroll
    for (int r = 0; r < 4; ++r) {
#pragma unroll
        for (int ms = 1; ms < 16; ms <<= 1) sumr[r] += __shfl_xor(sumr[r], ms);
    }
    if (lr == 0) {
#pragma unroll
        for (int r = 0; r < 4; ++r) sums[wid * 16 + g * 4 + r] = sumr[r];
    }
    __syncthreads();

    // epilogue: normalize, fold V-BN, GELU
    float svv[2], tvv[2];
#pragma unroll
    for (int dtl = 0; dtl < 2; ++dtl) {
        int ch = h * 192 + 64 + wid * 32 + dtl * 16 + lr;
        svv[dtl] = scale1[ch];
        tvv[dtl] = shift1[ch];
    }
#pragma unroll
    for (int qw = 0; qw < 4; ++qw) {
#pragma unroll
        for (int r = 0; r < 4; ++r) {
            float inv = __builtin_amdgcn_rcpf(sums[qw * 16 + g * 4 + r]);
            size_t nrow = (size_t)b * 320 + qt * 64 + qw * 16 + g * 4 + r;
#pragma unroll
            for (int dtl = 0; dtl < 2; ++dtl) {
                float v = oacc[qw][dtl][r] * inv * svv[dtl] + tvv[dtl];
                attnout[nrow * 1024 + h * 128 + wid * 32 + dtl * 16 + lr] = f2bf(gelu_f(v));
            }
        }
    }
}

// BN2 finalize folded into apply
__global__ void bn_apply(float* __restrict__ out, const float* __restrict__ sum2,
                         const float* __restrict__ sumsq2, const float* __restrict__ g2,
                         const float* __restrict__ b2) {
    __shared__ float sc[256], sh[256];
    {
        int c = threadIdx.x;
        float mean = sum2[c] * (1.0f / MROWS);
        float var = sumsq2[c] * (1.0f / MROWS) - mean * mean;
        float s = g2[c] * rsqrtf(var + EPS);
        sc[c] = s;
        sh[c] = b2[c] - mean * s;
    }
    __syncthreads();
    int i = blockIdx.x * 256 + threadIdx.x;
    const int total = MROWS * C_ / 4;
    for (; i < total; i += gridDim.x * 256) {
        f32x4 v = *(const f32x4*)&out[(size_t)i * 4];
        int c = (i * 4) & 255;
        f32x4 o;
#pragma unroll
        for (int j = 0; j < 4; ++j) o[j] = v[j] * sc[c + j] + sh[c + j];
        *(f32x4*)&out[(size_t)i * 4] = o;
    }
}

extern "C" void kernel_launch(void* const* d_in, const int* in_sizes, int n_in,
                              void* d_out, int out_size, void* d_ws, size_t ws_size,
                              hipStream_t stream) {
    const float* x = (const float*)d_in[0];
    const float* Wqkv = (const float*)d_in[1];
    const float* g1 = (const float*)d_in[2];
    const float* b1 = (const float*)d_in[3];
    const float* ab = (const float*)d_in[4];
    const float* Wproj = (const float*)d_in[5];
    const float* g2 = (const float*)d_in[6];
    const float* b2 = (const float*)d_in[7];
    const int* idxs = (const int*)d_in[8];
    const int n_off = in_sizes[4] / H_;

    char* ws = (char*)d_ws;
    unsigned short* qkB = (unsigned short*)ws;                       // 41.9MB
    unsigned short* vT = (unsigned short*)(ws + 41943040);           // 83.9MB
    unsigned short* attnout = (unsigned short*)(ws + 125829120);     // 83.9MB
    unsigned short* xb = attnout;                                    // overlap: dead before attn
    unsigned short* biasb = (unsigned short*)(ws + 209715200);       // bf16, re-tiled, *log2e
    float* uk = (float*)(ws + 212992000);
    unsigned short* wqb = (unsigned short*)(ws + 214302720);
    unsigned short* wpb = (unsigned short*)(ws + 215089152);
    float* stats = (float*)(ws + 215613440);
    float* sum1 = stats;
    float* sumsq1 = stats + 1536;
    float* sum2 = stats + 3072;
    float* sumsq2 = sum2 + 256;
    float* scale1 = sumsq2 + 256;
    float* shift1 = scale1 + 1536;

    hipMemsetAsync(stats, 0, 3584 * 4, stream);
    conv_all<<<dim3(10880), 256, 0, stream>>>(x, Wqkv, Wproj, xb, wqb, wpb);
    bias_build<<<dim3(3200), 256, 0, stream>>>(ab, idxs, biasb, n_off);
    gemm_qkv<<<dim3(1920), 512, 0, stream>>>(xb, wqb, qkB, vT, sum1, sumsq1);
    bn_finalize<<<dim3(6), 256, 0, stream>>>(sum1, sumsq1, g1, b1, scale1, shift1, 1536, 1.0f / MROWS);
    uk_kernel<<<dim3(1280), 256, 0, stream>>>(qkB, scale1, shift1, uk);
    attn_kernel<<<dim3(8, 640), 256, 0, stream>>>(qkB, vT, uk, biasb, scale1, shift1, attnout);
    gemm_proj<<<dim3(640), 256, 0, stream>>>(attnout, wpb, (float*)d_out, sum2, sumsq2);
    bn_apply<<<dim3(2048), 256, 0, stream>>>((float*)d_out, sum2, sumsq2, g2, b2);
}

// Round 22
// 276.344 us; speedup vs baseline: 1.0381x; 1.0080x over previous
//
#include <hip/hip_runtime.h>
#include <hip/hip_bf16.h>

#define B_ 128
#define N_ 320
#define C_ 256
#define H_ 8
#define HQKV 1536
#define DH 1024
#define MROWS 40960
#define EPS 1e-5f
#define SCALE 0.17677669529663687f
#define LOG2E 1.4426950408889634f

typedef __attribute__((ext_vector_type(4))) float f32x4;
typedef __attribute__((ext_vector_type(8))) short short8_t;
typedef __attribute__((ext_vector_type(4))) short short4_t;
typedef __attribute__((ext_vector_type(4))) unsigned short ushort4_t;

__device__ inline float bf2f(unsigned short u) { return __uint_as_float(((unsigned)u) << 16); }
__device__ inline unsigned short f2bf(float f) {
    unsigned u = __float_as_uint(f);
    u += 0x7FFF + ((u >> 16) & 1);
    return (unsigned short)(u >> 16);
}

// sigmoid-form tanh-GELU (8 VALU ops)
__device__ inline float gelu_f(float v) {
    float v2 = v * v;
    float w = fmaf(v2, 0.044715f, 1.0f);
    float z = v * w * (-2.3022098f);
    float e = __builtin_amdgcn_exp2f(z);
    return v * __builtin_amdgcn_rcpf(1.0f + e);
}

#define GLD16(gp, lp)                                                                  \
    __builtin_amdgcn_global_load_lds((const __attribute__((address_space(1))) void*)(gp), \
                                     (__attribute__((address_space(3))) void*)(lp), 16, 0, 0)

__global__ void conv_all(const float* __restrict__ x, const float* __restrict__ wqkv,
                         const float* __restrict__ wproj, unsigned short* __restrict__ xb,
                         unsigned short* __restrict__ wqb, unsigned short* __restrict__ wpb) {
    int i = blockIdx.x * 256 + threadIdx.x;
    const float* src;
    unsigned short* dst;
    int off;
    if (i < 2621440) { src = x; dst = xb; off = i; }
    else if (i < 2719744) { src = wqkv; dst = wqb; off = i - 2621440; }
    else if (i < 2785280) { src = wproj; dst = wpb; off = i - 2719744; }
    else return;
    f32x4 v = ((const f32x4*)src)[off];
    short4_t o;
#pragma unroll
    for (int j = 0; j < 4; ++j) o[j] = (short)f2bf(v[j]);
    ((short4_t*)dst)[off] = o;
}

// ---- GEMM1: 128x256 tile, 512 threads (8 waves 2Mx4N), 2-phase dbuf, XCD swizzle,
// routes q/k/v, fused BN stats ----
__global__ __launch_bounds__(512, 4) void gemm_qkv(const unsigned short* __restrict__ A,
                                                   const unsigned short* __restrict__ Bm,
                                                   unsigned short* __restrict__ qkB,
                                                   unsigned short* __restrict__ vT,
                                                   float* __restrict__ sum1,
                                                   float* __restrict__ sumsq1) {
    __shared__ unsigned short lA[2][128 * 32];
    __shared__ unsigned short lB[2][256 * 32];
    const int tid = threadIdx.x;
    const int lane = tid & 63, wid = tid >> 6;
    const int wm = wid >> 2, wn = wid & 3;
    const int lr = lane & 15, g = lane >> 4, lk = g * 8;
    const int orig = blockIdx.x;
    const int id2 = (orig & 7) * 240 + (orig >> 3);
    const int m0 = (id2 / 6) * 128, n0 = (id2 % 6) * 256;
    const int wb0 = tid & 448;

#define STAGE_QKV(it, buf)                                                               \
    {                                                                                    \
        int k0 = (it) * 32;                                                              \
        GLD16(&A[(size_t)(m0 + (tid >> 2)) * 256 + k0 + (tid & 3) * 8],                  \
              &lA[buf][(size_t)wb0 * 8]);                                                \
        GLD16(&Bm[(size_t)(n0 + (tid >> 2)) * 256 + k0 + (tid & 3) * 8],                 \
              &lB[buf][(size_t)wb0 * 8]);                                                \
        GLD16(&Bm[(size_t)(n0 + 128 + (tid >> 2)) * 256 + k0 + (tid & 3) * 8],           \
              &lB[buf][4096 + (size_t)wb0 * 8]);                                         \
    }

    STAGE_QKV(0, 0);
    f32x4 acc[4][4] = {};
    for (int it = 0; it < 8; ++it) {
        __syncthreads();
        if (it < 7) STAGE_QKV(it + 1, (it + 1) & 1);
        const unsigned short* la = lA[it & 1];
        const unsigned short* lb = lB[it & 1];
        short8_t af[4], bfr[4];
#pragma unroll
        for (int i = 0; i < 4; ++i) af[i] = *(const short8_t*)&la[(wm * 64 + i * 16 + lr) * 32 + lk];
#pragma unroll
        for (int j = 0; j < 4; ++j) bfr[j] = *(const short8_t*)&lb[(wn * 64 + j * 16 + lr) * 32 + lk];
#pragma unroll
        for (int i = 0; i < 4; ++i)
#pragma unroll
            for (int j = 0; j < 4; ++j)
                acc[i][j] = __builtin_amdgcn_mfma_f32_16x16x32_bf16(af[i], bfr[j], acc[i][j], 0, 0, 0);
    }
    int hhj[4], cmj[4];
#pragma unroll
    for (int j = 0; j < 4; ++j) {
        int col = n0 + wn * 64 + j * 16 + lr;
        hhj[j] = col / 192;
        cmj[j] = col - hhj[j] * 192;
    }
    float cs[4] = {0.f, 0.f, 0.f, 0.f}, css[4] = {0.f, 0.f, 0.f, 0.f};
#pragma unroll
    for (int i = 0; i < 4; ++i) {
        int rowbase = m0 + wm * 64 + i * 16 + g * 4;
        int bq = rowbase / 320;
        int n = rowbase - bq * 320;
#pragma unroll
        for (int j = 0; j < 4; ++j) {
            float v0 = acc[i][j][0], v1 = acc[i][j][1], v2 = acc[i][j][2], v3 = acc[i][j][3];
            cs[j] += (v0 + v1) + (v2 + v3);
            css[j] += (v0 * v0 + v1 * v1) + (v2 * v2 + v3 * v3);
            if (cmj[j] < 64) {
                unsigned short* qp = &qkB[((size_t)(bq * 8 + hhj[j]) * 320 + n) * 64 + cmj[j]];
                qp[0] = f2bf(v0); qp[64] = f2bf(v1); qp[128] = f2bf(v2); qp[192] = f2bf(v3);
            } else {
                short4_t o;
                o[0] = (short)f2bf(v0); o[1] = (short)f2bf(v1);
                o[2] = (short)f2bf(v2); o[3] = (short)f2bf(v3);
                *(short4_t*)&vT[((size_t)(bq * 8 + hhj[j]) * 128 + (cmj[j] - 64)) * 320 + n] = o;
            }
        }
    }
    __syncthreads();
    float* red_s = (float*)lA;
    float* red_ss = (float*)lB;
#pragma unroll
    for (int j = 0; j < 4; ++j) {
        int c = wn * 64 + j * 16 + lr;
        red_s[(wm * 4 + g) * 256 + c] = cs[j];
        red_ss[(wm * 4 + g) * 256 + c] = css[j];
    }
    __syncthreads();
    if (tid < 256) {
        float s = 0.f;
#pragma unroll
        for (int u = 0; u < 8; ++u) s += red_s[u * 256 + tid];
        atomicAdd(&sum1[n0 + tid], s);
    } else if (tid < 512) {
        int c = tid - 256;
        float s = 0.f;
#pragma unroll
        for (int u = 0; u < 8; ++u) s += red_ss[u * 256 + c];
        atomicAdd(&sumsq1[n0 + c], s);
    }
}

// ---- GEMM2: 64x256 tile (single N-tile: A read once), 2-phase dbuf, fused stats ----
__global__ __launch_bounds__(256, 4) void gemm_proj(const unsigned short* __restrict__ A,
                                                    const unsigned short* __restrict__ Bm,
                                                    float* __restrict__ Cout,
                                                    float* __restrict__ sum2,
                                                    float* __restrict__ sumsq2) {
    __shared__ unsigned short lA[2][64 * 32];
    __shared__ unsigned short lB[2][256 * 32];
    const int tid = threadIdx.x;
    const int lane = tid & 63, wid = tid >> 6;
    const int wn = wid;
    const int lr = lane & 15, g = lane >> 4, lk = g * 8;
    const int m0 = blockIdx.x * 64;
    const int wb0 = tid & 192;

#define STAGE_PROJ(it, buf)                                                              \
    {                                                                                    \
        int k0 = (it) * 32;                                                              \
        GLD16(&A[(size_t)(m0 + (tid >> 2)) * 1024 + k0 + (tid & 3) * 8],                 \
              &lA[buf][(size_t)wb0 * 8]);                                                \
        GLD16(&Bm[(size_t)(tid >> 2) * 1024 + k0 + (tid & 3) * 8],                       \
              &lB[buf][(size_t)wb0 * 8]);                                                \
        GLD16(&Bm[(size_t)(64 + (tid >> 2)) * 1024 + k0 + (tid & 3) * 8],                \
              &lB[buf][2048 + (size_t)wb0 * 8]);                                         \
        GLD16(&Bm[(size_t)(128 + (tid >> 2)) * 1024 + k0 + (tid & 3) * 8],               \
              &lB[buf][4096 + (size_t)wb0 * 8]);                                         \
        GLD16(&Bm[(size_t)(192 + (tid >> 2)) * 1024 + k0 + (tid & 3) * 8],               \
              &lB[buf][6144 + (size_t)wb0 * 8]);                                         \
    }

    STAGE_PROJ(0, 0);
    f32x4 acc[4][4] = {};
    for (int it = 0; it < 32; ++it) {
        __syncthreads();
        if (it < 31) STAGE_PROJ(it + 1, (it + 1) & 1);
        const unsigned short* la = lA[it & 1];
        const unsigned short* lb = lB[it & 1];
        short8_t af[4], bfr[4];
#pragma unroll
        for (int i = 0; i < 4; ++i) af[i] = *(const short8_t*)&la[(i * 16 + lr) * 32 + lk];
#pragma unroll
        for (int j = 0; j < 4; ++j) bfr[j] = *(const short8_t*)&lb[(wn * 64 + j * 16 + lr) * 32 + lk];
#pragma unroll
        for (int i = 0; i < 4; ++i)
#pragma unroll
            for (int j = 0; j < 4; ++j)
                acc[i][j] = __builtin_amdgcn_mfma_f32_16x16x32_bf16(af[i], bfr[j], acc[i][j], 0, 0, 0);
    }
    float cs[4] = {0.f, 0.f, 0.f, 0.f}, css[4] = {0.f, 0.f, 0.f, 0.f};
#pragma unroll
    for (int i = 0; i < 4; ++i) {
#pragma unroll
        for (int r = 0; r < 4; ++r) {
            int row = m0 + i * 16 + g * 4 + r;
#pragma unroll
            for (int j = 0; j < 4; ++j) {
                float val = acc[i][j][r];
                cs[j] += val;
                css[j] += val * val;
                Cout[(size_t)row * 256 + wn * 64 + j * 16 + lr] = val;
            }
        }
    }
    __syncthreads();
    float* red_s = (float*)lA;
    float* red_ss = (float*)lB;
#pragma unroll
    for (int j = 0; j < 4; ++j) {
        int c = wn * 64 + j * 16 + lr;
        red_s[g * 256 + c] = cs[j];
        red_ss[g * 256 + c] = css[j];
    }
    __syncthreads();
    {
        float s = 0.f, ss = 0.f;
#pragma unroll
        for (int u = 0; u < 4; ++u) {
            s += red_s[u * 256 + tid];
            ss += red_ss[u * 256 + tid];
        }
        atomicAdd(&sum2[tid], s);
        atomicAdd(&sumsq2[tid], ss);
    }
}

__global__ void bn_finalize(const float* __restrict__ sum, const float* __restrict__ sumsq,
                            const float* __restrict__ g, const float* __restrict__ b,
                            float* __restrict__ scale, float* __restrict__ shift, int C, float invM) {
    int c = blockIdx.x * 256 + threadIdx.x;
    if (c < C) {
        float mean = sum[c] * invM;
        float var = sumsq[c] * invM - mean * mean;
        float sc = g[c] * rsqrtf(var + EPS);
        scale[c] = sc;
        shift[c] = b[c] - mean * sc;
    }
}

// uk with w2 built in LDS preamble
__global__ void uk_kernel(const unsigned short* __restrict__ qkB, const float* __restrict__ scale1,
                          const float* __restrict__ shift1, float* __restrict__ uk) {
    __shared__ float w2l[256];
    {
        int c = threadIdx.x;
        int hh = c >> 5, cc = c & 31;
        int qch = hh * 192 + cc;
        w2l[c] = shift1[qch] * scale1[qch + 32] * (SCALE * LOG2E);
    }
    __syncthreads();
    int idx = blockIdx.x * 256 + threadIdx.x;
    if (idx < 128 * 8 * 320) {
        int bh = idx / 320;
        int h = bh & 7;
        const unsigned short* kp = &qkB[(size_t)idx * 64 + 32];
        float s = 0.f;
#pragma unroll
        for (int c4 = 0; c4 < 4; ++c4) {
            short8_t kk = *(const short8_t*)&kp[c4 * 8];
#pragma unroll
            for (int j = 0; j < 8; ++j) s += bf2f((unsigned short)kk[j]) * w2l[(h << 5) + c4 * 8 + j];
        }
        uk[idx] = s;
    }
}

// bias re-tiled: biasb[((h*80 + n/4)*320 + m)*4 + (n%4)] = bf16(ab[h][idxs[n][m]]*log2e)
__global__ void bias_build(const float* __restrict__ ab, const int* __restrict__ idxs,
                           unsigned short* __restrict__ biasb, int n_off) {
    int i = blockIdx.x * 256 + threadIdx.x;
    if (i < H_ * N_ * N_) {
        int r = i & 3;
        int m = (i >> 2) % 320;
        int nq = ((i >> 2) / 320) % 80;
        int h = i / 102400;
        int n = nq * 4 + r;
        biasb[i] = f2bf(ab[h * n_off + idxs[n * 320 + m]] * LOG2E);
    }
}

// ---- attention v13: R19 + V-load hoist across the barrier (T14-style issue-early).
// V fragments for each half are loaded into registers BEFORE the syncthreads so the
// first PV MFMA after the barrier doesn't eat cold L2 latency. Peak regs ~95 (sacc dead
// at issue point) -> spill-free at (256,4). ----
__global__ __launch_bounds__(256, 4) void attn_kernel(const unsigned short* __restrict__ qkB,
                                                      const unsigned short* __restrict__ vT,
                                                      const float* __restrict__ uk,
                                                      const unsigned short* __restrict__ biasb,
                                                      const float* __restrict__ scale1,
                                                      const float* __restrict__ shift1,
                                                      unsigned short* __restrict__ attnout) {
    __shared__ unsigned short Plds[4][5][16][40];
    __shared__ float sums[64];
    const int tid = threadIdx.x;
    const int lane = tid & 63, wid = tid >> 6;
    const int lr = lane & 15, g = lane >> 4;
    const int h = blockIdx.x;
    const int b = blockIdx.y / 5, qt = blockIdx.y % 5;
    const int bh = b * 8 + h;

    int qrow = qt * 64 + wid * 16 + lr;
    short8_t qraw = *(const short8_t*)&qkB[((size_t)bh * 320 + qrow) * 64 + g * 8];
    short8_t aq;
    const int cq = h * 192 + g * 8;
#pragma unroll
    for (int j = 0; j < 8; ++j) {
        float w = scale1[cq + j] * scale1[cq + 32 + j] * (SCALE * LOG2E);
        aq[j] = (short)f2bf(bf2f((unsigned short)qraw[j]) * w);
    }

    const unsigned short* Kbase = &qkB[(size_t)bh * 320 * 64 + 32 + g * 8];
    const int nloc0 = qt * 64 + wid * 16 + g * 4;
    const unsigned short* biasrow = &biasb[((size_t)h * 80 + (nloc0 >> 2)) * 1280];
    const float* ukrow = &uk[(size_t)bh * 320];
    const unsigned short* Vb = &vT[(size_t)bh * 128 * 320 + g * 8];

    float sumr[4] = {0.f, 0.f, 0.f, 0.f};
    f32x4 oacc[4][2] = {};
#pragma unroll
    for (int half = 0; half < 2; ++half) {
        const int mb = half * 160;
        // phase 1: 10 QK^T MFMAs for this half
        f32x4 sacc[10];
        __builtin_amdgcn_s_setprio(1);
#pragma unroll
        for (int t = 0; t < 10; ++t) {
            short8_t bk = *(const short8_t*)&Kbase[(size_t)(mb + t * 16 + lr) * 64];
            f32x4 z = {};
            sacc[t] = __builtin_amdgcn_mfma_f32_16x16x32_bf16(aq, bk, z, 0, 0, 0);
        }
        __builtin_amdgcn_s_setprio(0);
        // phase 2: coalesced ushort4 bias + uk + exp2 -> P slab
#pragma unroll
        for (int t = 0; t < 10; ++t) {
            int m = mb + t * 16 + lr;
            float ukv = ukrow[m];
            ushort4_t b4 = *(const ushort4_t*)&biasrow[m * 4];
#pragma unroll
            for (int r = 0; r < 4; ++r) {
                float s = sacc[t][r] + ukv + bf2f(b4[r]);
                float p = __builtin_amdgcn_exp2f(s);
                sumr[r] += p;
                Plds[wid][t >> 1][g * 4 + r][(t & 1) * 16 + lr] = f2bf(p);
            }
        }
        // V-load hoist: issue all 10 V fragment loads BEFORE the barrier (addresses are
        // barrier-independent); latency hides under barrier convergence.
        short8_t vf0[5], vf1[5];
#pragma unroll
        for (int t = 0; t < 5; ++t) {
            vf0[t] = *(const short8_t*)&Vb[(size_t)(wid * 32 + lr) * 320 + mb + t * 32];
            vf1[t] = *(const short8_t*)&Vb[(size_t)(wid * 32 + 16 + lr) * 320 + mb + t * 32];
        }
        __syncthreads();
        // phase 3: PV for this half; wave owns O-cols [wid*32, +32); reads all 4 P slabs
        __builtin_amdgcn_s_setprio(1);
#pragma unroll
        for (int t = 0; t < 5; ++t) {
#pragma unroll
            for (int qw = 0; qw < 4; ++qw) {
                short8_t ap = *(short8_t*)&Plds[qw][t][lr][g * 8];
                oacc[qw][0] = __builtin_amdgcn_mfma_f32_16x16x32_bf16(ap, vf0[t], oacc[qw][0], 0, 0, 0);
                oacc[qw][1] = __builtin_amdgcn_mfma_f32_16x16x32_bf16(ap, vf1[t], oacc[qw][1], 0, 0, 0);
            }
        }
        __builtin_amdgcn_s_setprio(0);
        __syncthreads();  // Plds reused next half
    }

    // rowsum reduce + publish
#pragma unroll
    for (int r = 0; r < 4; ++r) {
#pragma unroll
        for (int ms = 1; ms < 16; ms <<= 1) sumr[r] += __shfl_xor(sumr[r], ms);
    }
    if (lr == 0) {
#pragma unroll
        for (int r = 0; r < 4; ++r) sums[wid * 16 + g * 4 + r] = sumr[r];
    }
    __syncthreads();

    // epilogue: normalize, fold V-BN, GELU
    float svv[2], tvv[2];
#pragma unroll
    for (int dtl = 0; dtl < 2; ++dtl) {
        int ch = h * 192 + 64 + wid * 32 + dtl * 16 + lr;
        svv[dtl] = scale1[ch];
        tvv[dtl] = shift1[ch];
    }
#pragma unroll
    for (int qw = 0; qw < 4; ++qw) {
#pragma unroll
        for (int r = 0; r < 4; ++r) {
            float inv = __builtin_amdgcn_rcpf(sums[qw * 16 + g * 4 + r]);
            size_t nrow = (size_t)b * 320 + qt * 64 + qw * 16 + g * 4 + r;
#pragma unroll
            for (int dtl = 0; dtl < 2; ++dtl) {
                float v = oacc[qw][dtl][r] * inv * svv[dtl] + tvv[dtl];
                attnout[nrow * 1024 + h * 128 + wid * 32 + dtl * 16 + lr] = f2bf(gelu_f(v));
            }
        }
    }
}

// BN2 finalize folded into apply
__global__ void bn_apply(float* __restrict__ out, const float* __restrict__ sum2,
                         const float* __restrict__ sumsq2, const float* __restrict__ g2,
                         const float* __restrict__ b2) {
    __shared__ float sc[256], sh[256];
    {
        int c = threadIdx.x;
        float mean = sum2[c] * (1.0f / MROWS);
        float var = sumsq2[c] * (1.0f / MROWS) - mean * mean;
        float s = g2[c] * rsqrtf(var + EPS);
        sc[c] = s;
        sh[c] = b2[c] - mean * s;
    }
    __syncthreads();
    int i = blockIdx.x * 256 + threadIdx.x;
    const int total = MROWS * C_ / 4;
    for (; i < total; i += gridDim.x * 256) {
        f32x4 v = *(const f32x4*)&out[(size_t)i * 4];
        int c = (i * 4) & 255;
        f32x4 o;
#pragma unroll
        for (int j = 0; j < 4; ++j) o[j] = v[j] * sc[c + j] + sh[c + j];
        *(f32x4*)&out[(size_t)i * 4] = o;
    }
}

extern "C" void kernel_launch(void* const* d_in, const int* in_sizes, int n_in,
                              void* d_out, int out_size, void* d_ws, size_t ws_size,
                              hipStream_t stream) {
    const float* x = (const float*)d_in[0];
    const float* Wqkv = (const float*)d_in[1];
    const float* g1 = (const float*)d_in[2];
    const float* b1 = (const float*)d_in[3];
    const float* ab = (const float*)d_in[4];
    const float* Wproj = (const float*)d_in[5];
    const float* g2 = (const float*)d_in[6];
    const float* b2 = (const float*)d_in[7];
    const int* idxs = (const int*)d_in[8];
    const int n_off = in_sizes[4] / H_;

    char* ws = (char*)d_ws;
    unsigned short* qkB = (unsigned short*)ws;                       // 41.9MB
    unsigned short* vT = (unsigned short*)(ws + 41943040);           // 83.9MB
    unsigned short* attnout = (unsigned short*)(ws + 125829120);     // 83.9MB
    unsigned short* xb = attnout;                                    // overlap: dead before attn
    unsigned short* biasb = (unsigned short*)(ws + 209715200);       // bf16, re-tiled, *log2e
    float* uk = (float*)(ws + 212992000);
    unsigned short* wqb = (unsigned short*)(ws + 214302720);
    unsigned short* wpb = (unsigned short*)(ws + 215089152);
    float* stats = (float*)(ws + 215613440);
    float* sum1 = stats;
    float* sumsq1 = stats + 1536;
    float* sum2 = stats + 3072;
    float* sumsq2 = sum2 + 256;
    float* scale1 = sumsq2 + 256;
    float* shift1 = scale1 + 1536;

    hipMemsetAsync(stats, 0, 3584 * 4, stream);
    conv_all<<<dim3(10880), 256, 0, stream>>>(x, Wqkv, Wproj, xb, wqb, wpb);
    bias_build<<<dim3(3200), 256, 0, stream>>>(ab, idxs, biasb, n_off);
    gemm_qkv<<<dim3(1920), 512, 0, stream>>>(xb, wqb, qkB, vT, sum1, sumsq1);
    bn_finalize<<<dim3(6), 256, 0, stream>>>(sum1, sumsq1, g1, b1, scale1, shift1, 1536, 1.0f / MROWS);
    uk_kernel<<<dim3(1280), 256, 0, stream>>>(qkB, scale1, shift1, uk);
    attn_kernel<<<dim3(8, 640), 256, 0, stream>>>(qkB, vT, uk, biasb, scale1, shift1, attnout);
    gemm_proj<<<dim3(640), 256, 0, stream>>>(attnout, wpb, (float*)d_out, sum2, sumsq2);
    bn_apply<<<dim3(2048), 256, 0, stream>>>((float*)d_out, sum2, sumsq2, g2, b2);
}